// Round 7
// baseline (660.731 us; speedup 1.0000x reference)
//
#include <hip/hip_runtime.h>
#include <math.h>

#define NB 256      // batch / time steps
#define NV 100      // visits
#define NC 40       // codes per visit
#define NE 128      // embed dim (LSTM "batch")
#define NH 100      // hidden (== feat)
#define NG 400      // 4*NH

// ws layout (float elements). sumembed + last are GONE (embed fused into
// the producer blocks; last travels inside the flag value).
#define OFF_PRE   0
#define N_PRE     (NB*NE*NG)                 // 13,107,200
#define OFF_TRUH  (OFF_PRE + N_PRE)
#define N_TRUH    (NB*NE)                    // 32,768
#define OFF_FLAG  (OFF_TRUH + N_TRUH)        // 256 ints

__device__ __forceinline__ float fast_sigmoid(float x) {
  return 1.f / (1.f + __expf(-x));
}
__device__ __forceinline__ float fast_tanh(float x) {
  float ax = fabsf(x);
  float e  = __expf(-2.f * ax);
  float t  = (1.f - e) / (1.f + e);
  return x < 0.f ? -t : t;
}

#define FMA4(A, W, H)                                                     \
  A = fmaf((H).x, (W).x, A); A = fmaf((H).y, (W).y, A);                   \
  A = fmaf((H).z, (W).z, A); A = fmaf((H).w, (W).w, A)

// ---------------------------------------------------------------- fused
// Producer/consumer fusion. 256 blocks x 512 threads.
//   blocks 0..127   : producers. tiles t = bid, bid+128. Per tile:
//                     embed (b==t, all v,e) straight into As in LDS,
//                     then 128x400 GEMM vs W_ih in 128-wide n-chunks,
//                     store pre[t], release flag[t] = last[t]+2.
//   blocks 128..255 : consumers. e = bid-128. Exact R0 LSTM core; the
//                     pre[t+3] prefetch is gated on flag[t+3] via a
//                     wave-parallel acquire-probe (ballot prefix), so no
//                     pre line is ever read before its release -> no
//                     stale-cache hazard by construction.
// 106.6KB static LDS forces 1 block/CU: all 256 blocks co-resident on
// 256 CUs (spin-wait cannot deadlock; producers never share a CU with a
// consumer). Producers never wait on anyone.
// All per-value arithmetic (embed chain, GEMM chain+bias, LSTM ladder)
// is bit-identical to the R5/R6 passing kernels.
__global__ __launch_bounds__(512, 2) void k_fused(
    const int* __restrict__ diag, const float* __restrict__ mask,
    const float* __restrict__ table, const float* __restrict__ Wih,
    const float* __restrict__ bih, const float* __restrict__ bhh,
    const float* __restrict__ Whh, float* __restrict__ pre,
    int* __restrict__ flag, float* __restrict__ truh) {
  // producer LDS
  __shared__ __align__(16) float As[100][132];   // [k][m], 128 + 4 pad
  __shared__ __align__(16) float Bs[100][132];   // [k][n], 128 + 4 pad
  __shared__ __align__(16) float bias_s[128];
  __shared__ int lastred[4];
  // consumer LDS
  __shared__ __align__(16) float h_s[100];
  __shared__ float g_s[NG];
  __shared__ int   last_s[NB];
  __shared__ int   ready_s;

  const int tid = threadIdx.x;
  const int bid = blockIdx.x;

  if (bid < 128) {
    // ============================ producer ============================
    const int e   = tid & 127;
    const int sub = tid >> 7;                    // 0..3
    for (int rep = 0; rep < 2; ++rep) {
      const int t = bid + rep * 128;             // rep0: t=0..127 in parallel
      // ---- embed b==t into As. f = 12800*t + fl; fl = i*512 + tid.
      // e = fl%128 = tid&127 (const per thread); v = fl>>7 (wave-uniform).
      int vmax = -1;
      for (int i = 0; i < 25; ++i) {
        int fl = i * 512 + tid;
        int v  = fl >> 7;                        // 0..99, wave-uniform
        const float* mrow = mask + (t * NV + v) * NC;  // uniform -> s_load
        const int*   drow = diag + (t * NV + v) * NC;
        float acc = 0.f, msum = 0.f;
        #pragma unroll 8
        for (int c = 0; c < NC; ++c) {
          float mm = mrow[c];
          int idx  = drow[c];
          acc = fmaf(mm, table[idx * NE + e], acc);  // identical chain
          msum += mm;
        }
        int m = fl / 100, k = fl - m * 100;
        As[k][m] = acc;                          // As[k][m] == x2[t*128+m][k]
        if (e == 0 && msum > 0.f) vmax = max(vmax, v);
      }
      if (e == 0) lastred[sub] = vmax;           // sub covers v%4==sub
      __syncthreads();                           // As + lastred ready
      int flagval = 0;
      if (tid == 0) {
        int l = max(max(lastred[0], lastred[1]), max(lastred[2], lastred[3]));
        flagval = l + 2;                         // >=1; consumer does -2
      }
      // ---- GEMM: 128m x 400n in 128-wide n-chunks (R5 math per output)
      const int tm = tid & 15, tn = tid >> 4;    // 16 x 32 thread grid
      for (int n0 = 0; n0 < NG; n0 += 128) {
        for (int idx = tid; idx < 12800; idx += 512) {
          int n = idx / 100, k = idx - n * 100;
          int jc = n0 + n;
          Bs[k][n] = (jc < NG) ? Wih[jc * 100 + k] : 0.f;
        }
        if (tid < 128) {
          int jc = n0 + tid;
          bias_s[tid] = (jc < NG) ? (bih[jc] + bhh[jc]) : 0.f;
        }
        __syncthreads();
        float acc[8][4] = {};
        #define PG_FMA(R, AX)                                             \
          acc[R][0] = fmaf(AX, bb.x, acc[R][0]);                          \
          acc[R][1] = fmaf(AX, bb.y, acc[R][1]);                          \
          acc[R][2] = fmaf(AX, bb.z, acc[R][2]);                          \
          acc[R][3] = fmaf(AX, bb.w, acc[R][3]);
        #pragma unroll 2
        for (int k = 0; k < 100; ++k) {
          float4 a0 = *(const float4*)&As[k][tm * 4];       // 2-way, free
          float4 a1 = *(const float4*)&As[k][64 + tm * 4];
          float4 bb = *(const float4*)&Bs[k][tn * 4];       // broadcast
          PG_FMA(0, a0.x) PG_FMA(1, a0.y) PG_FMA(2, a0.z) PG_FMA(3, a0.w)
          PG_FMA(4, a1.x) PG_FMA(5, a1.y) PG_FMA(6, a1.z) PG_FMA(7, a1.w)
        }
        #undef PG_FMA
        if (n0 + tn * 4 < NG) {                  // whole float4 valid or none
          float4 bv4 = *(const float4*)&bias_s[tn * 4];
          #pragma unroll
          for (int r = 0; r < 8; ++r) {
            int m = t * 128 + ((r < 4) ? (tm * 4 + r) : (64 + tm * 4 + (r - 4)));
            float4 st;
            st.x = acc[r][0] + bv4.x; st.y = acc[r][1] + bv4.y;
            st.z = acc[r][2] + bv4.z; st.w = acc[r][3] + bv4.w;
            *(float4*)&pre[m * NG + n0 + tn * 4] = st;
          }
        }
        __syncthreads();                         // stores drained (vmcnt) +
      }                                          // Bs safe to overwrite
      if (tid == 0) {
        __threadfence();                         // agent-scope: flush L2
        __hip_atomic_store(&flag[t], flagval, __ATOMIC_RELEASE,
                           __HIP_MEMORY_SCOPE_AGENT);
      }
      // next rep overwrites As: last chunk barrier above already covers it
    }
  } else {
    // ============================ consumer ============================
    const int e = bid - 128;          // 0..127
    const int j = tid;                // active < 400

    float4 w00, w01, w02, w03, w04, w05, w06, w07, w08, w09, w10, w11, w12,
           w13, w14, w15, w16, w17, w18, w19, w20, w21, w22, w23, w24;
    if (j < NG) {
      const float4* wr = (const float4*)(Whh + j * 100);
      w00 = wr[0];  w01 = wr[1];  w02 = wr[2];  w03 = wr[3];  w04 = wr[4];
      w05 = wr[5];  w06 = wr[6];  w07 = wr[7];  w08 = wr[8];  w09 = wr[9];
      w10 = wr[10]; w11 = wr[11]; w12 = wr[12]; w13 = wr[13]; w14 = wr[14];
      w15 = wr[15]; w16 = wr[16]; w17 = wr[17]; w18 = wr[18]; w19 = wr[19];
      w20 = wr[20]; w21 = wr[21]; w22 = wr[22]; w23 = wr[23]; w24 = wr[24];
    }
    if (j < NH) h_s[j] = 0.f;
    if (j == 0) ready_s = 0;
    float c = 0.f;
    const float* pbase = pre + e * NG + j;
    __syncthreads();

    int ready = 0;
    // Wave-parallel flag probe: lanes j<64 acquire-load flags
    // [ready, ready+64); advance by the contiguous-set prefix (ballot).
    // Acquire on each observed flag -> later pre loads are coherent even
    // across graph-replay iterations. Amortized ~1 round / 64 steps.
    #define ENSURE(NEED)                                                  \
      while (ready < (NEED)) {                                            \
        int f = 0;                                                        \
        int fidx = ready + j;                                             \
        if (j < 64 && fidx < NB)                                          \
          f = __hip_atomic_load(&flag[fidx], __ATOMIC_ACQUIRE,            \
                                __HIP_MEMORY_SCOPE_AGENT);                \
        if (f != 0) last_s[fidx] = f - 2;                                 \
        unsigned long long bal = __ballot(f != 0);                        \
        if (j == 0) {                                                     \
          int adv = (~bal == 0ULL) ? 64 : (__ffsll((long long)~bal) - 1); \
          ready_s = ready + adv;                                          \
        }                                                                 \
        __syncthreads();                                                  \
        ready = ready_s;                                                  \
        __syncthreads();                                                  \
      }

    ENSURE(3);
    float p0 = (j < NG) ? pbase[0]         : 0.f;
    float p1 = (j < NG) ? pbase[51200]     : 0.f;
    float p2 = (j < NG) ? pbase[2 * 51200] : 0.f;

    for (int t = 0; t < NB; ++t) {
      int need = (t + 4 < NB) ? (t + 4) : NB;
      ENSURE(need);                              // gates p3 AND last_s[t]
      float p3 = (j < NG && t + 3 < NB) ? pbase[(t + 3) * 51200] : 0.f;

      if (j < NG) {
        float a0 = p0, a1 = 0.f, a2 = 0.f, a3 = 0.f;
        const float4* h4 = (const float4*)h_s;
        float4 h;
        h = h4[0];  FMA4(a0, w00, h);
        h = h4[1];  FMA4(a1, w01, h);
        h = h4[2];  FMA4(a2, w02, h);
        h = h4[3];  FMA4(a3, w03, h);
        h = h4[4];  FMA4(a0, w04, h);
        h = h4[5];  FMA4(a1, w05, h);
        h = h4[6];  FMA4(a2, w06, h);
        h = h4[7];  FMA4(a3, w07, h);
        h = h4[8];  FMA4(a0, w08, h);
        h = h4[9];  FMA4(a1, w09, h);
        h = h4[10]; FMA4(a2, w10, h);
        h = h4[11]; FMA4(a3, w11, h);
        h = h4[12]; FMA4(a0, w12, h);
        h = h4[13]; FMA4(a1, w13, h);
        h = h4[14]; FMA4(a2, w14, h);
        h = h4[15]; FMA4(a3, w15, h);
        h = h4[16]; FMA4(a0, w16, h);
        h = h4[17]; FMA4(a1, w17, h);
        h = h4[18]; FMA4(a2, w18, h);
        h = h4[19]; FMA4(a3, w19, h);
        h = h4[20]; FMA4(a0, w20, h);
        h = h4[21]; FMA4(a1, w21, h);
        h = h4[22]; FMA4(a2, w22, h);
        h = h4[23]; FMA4(a3, w23, h);
        h = h4[24]; FMA4(a0, w24, h);
        float acc = (a0 + a1) + (a2 + a3);
        float act = (j >= 200 && j < 300) ? fast_tanh(acc) : fast_sigmoid(acc);
        g_s[j] = act;
      }
      __syncthreads();                           // gates visible

      if (j < NH) {
        float ig = g_s[j], fg = g_s[100 + j], gg = g_s[200 + j], og = g_s[300 + j];
        c = fmaf(fg, c, ig * gg);
        float h = og * fast_tanh(c);
        h_s[j] = h;
        if (j == last_s[t]) truh[t * NE + e] = h;
      }
      __syncthreads();                           // h_s(t) visible

      p0 = p1; p1 = p2; p2 = p3;
    }
    #undef ENSURE
  }
}

// ---------------------------------------------------------------- k_fc
// out[b] = sigmoid( truh[b,:] . fc_w + fc_b )   (ordered reduce: exact)
__global__ __launch_bounds__(128) void k_fc(
    const float* __restrict__ truh, const float* __restrict__ fcw,
    const float* __restrict__ fcb, float* __restrict__ out) {
  int b = blockIdx.x, t = threadIdx.x;
  float v = truh[b * NE + t] * fcw[t];
  #pragma unroll
  for (int o = 32; o > 0; o >>= 1) v += __shfl_down(v, o);
  __shared__ float s[2];
  if ((t & 63) == 0) s[t >> 6] = v;
  __syncthreads();
  if (t == 0) {
    float sum = s[0] + s[1] + fcb[0];
    out[b] = 1.f / (1.f + __expf(-sum));
  }
}

// ---------------------------------------------------------------- launch
extern "C" void kernel_launch(void* const* d_in, const int* in_sizes, int n_in,
                              void* d_out, int out_size, void* d_ws, size_t ws_size,
                              hipStream_t stream) {
  (void)in_sizes; (void)n_in; (void)out_size; (void)ws_size;
  const int*   diag  = (const int*)d_in[0];
  const float* mask  = (const float*)d_in[1];
  const float* table = (const float*)d_in[2];
  const float* Wih   = (const float*)d_in[3];
  const float* Whh   = (const float*)d_in[4];
  const float* bih   = (const float*)d_in[5];
  const float* bhh   = (const float*)d_in[6];
  const float* fcw   = (const float*)d_in[7];
  const float* fcb   = (const float*)d_in[8];

  float* ws   = (float*)d_ws;
  float* pre  = ws + OFF_PRE;
  float* truh = ws + OFF_TRUH;
  int*   flag = (int*)(ws + OFF_FLAG);
  float* out  = (float*)d_out;

  hipMemsetAsync(flag, 0, NB * sizeof(int), stream);   // must precede k_fused
  k_fused<<<dim3(256), dim3(512), 0, stream>>>(
      diag, mask, table, Wih, bih, bhh, Whh, pre, flag, truh);
  k_fc<<<dim3(NB), dim3(128), 0, stream>>>(truh, fcw, fcb, out);
}

// Round 8
// 403.566 us; speedup vs baseline: 1.6372x; 1.6372x over previous
//
#include <hip/hip_runtime.h>
#include <math.h>

#define NB 256      // batch / time steps
#define NV 100      // visits
#define NC 40       // codes per visit
#define NE 128      // embed dim (LSTM "batch")
#define NH 100      // hidden (== feat)
#define NG 400      // 4*NH

// ws layout (float elements). sumembed is GONE (embed fused into the
// GEMM's A-staging); last is a plain per-block store (no memset).
#define OFF_PRE   0
#define N_PRE     (NB*NE*NG)                 // 13,107,200
#define OFF_TRUH  (OFF_PRE + N_PRE)
#define N_TRUH    (NB*NE)                    // 32,768
#define OFF_LAST  (OFF_TRUH + N_TRUH)        // 256 ints

// ---------------------------------------------------------------- kernel 1
// Fused embed + pregemm. 256 blocks x 512 threads, t = blockIdx.x, one
// block per CU (105.6KB LDS), full-chip in a single round.
//
// R6/R7 POST-MORTEM: k_embed's cost was its 25,600-block DISPATCH (tiny
// blocks, launch-overhead-bound; R6's inner-work change was exactly
// neutral). R7 proved the embed->As fusion + this GEMM bit-exact
// (absmax 0) but strangled it with producer/consumer CU-splitting and
// spin-wait L2 interference. Here: same proven producer code, run as a
// plain grid-wide kernel. Deletes the k_embed dispatch, the 13.1MB
// sumembed round-trip, the hipMemset, and one launch gap.
//
// Embed: As[k][m] (m=fl/100, k=fl%100, fl=v*128+e) == x2[t*128+m][k],
// acc chain ascending c (identical numerics). last[t]: block-local
// reduction, plain store (block t is the only writer).
// GEMM: 128m x 400n in 4 n-chunks of 128; 8m x 4n per thread; same
// k-ascending fmaf chain + bias at store as R5 -> bit-identical.
__global__ __launch_bounds__(512, 2) void k_embgemm(
    const int* __restrict__ diag, const float* __restrict__ mask,
    const float* __restrict__ table, const float* __restrict__ Wih,
    const float* __restrict__ bih, const float* __restrict__ bhh,
    float* __restrict__ pre, int* __restrict__ last) {
  __shared__ __align__(16) float As[100][132];   // [k][m], 128 + 4 pad
  __shared__ __align__(16) float Bs[100][132];   // [k][n], 128 + 4 pad
  __shared__ __align__(16) float bias_s[128];
  __shared__ int lastred[4];

  const int tid = threadIdx.x;
  const int t   = blockIdx.x;                    // 0..255 == batch row
  const int e   = tid & 127;
  const int sub = tid >> 7;                      // 0..3

  // ---- embed b==t straight into As. fl = i*512 + tid; v = fl>>7
  // (wave-uniform), e = fl&127 (const per thread).
  int vmax = -1;
  for (int i = 0; i < 25; ++i) {
    int fl = i * 512 + tid;
    int v  = fl >> 7;                            // 0..99, wave-uniform
    const float* mrow = mask + (t * NV + v) * NC;  // uniform -> s_load
    const int*   drow = diag + (t * NV + v) * NC;
    float acc = 0.f, msum = 0.f;
    #pragma unroll 8
    for (int c = 0; c < NC; ++c) {
      float mm = mrow[c];
      int idx  = drow[c];
      acc = fmaf(mm, table[idx * NE + e], acc);  // identical chain
      msum += mm;
    }
    int m = fl / 100, k = fl - m * 100;
    As[k][m] = acc;                              // As[k][m] == x2[t*128+m][k]
    if (e == 0 && msum > 0.f) vmax = max(vmax, v);
  }
  if (e == 0) lastred[sub] = vmax;               // sub covers v%4==sub
  __syncthreads();                               // As + lastred ready
  if (tid == 0) {
    int l = max(max(lastred[0], lastred[1]), max(lastred[2], lastred[3]));
    last[t] = max(l, 0);                         // == memset0 + atomicMax
  }

  // ---- GEMM: 128m x 400n in 128-wide n-chunks (R5 math per output)
  const int tm = tid & 15, tn = tid >> 4;        // 16 x 32 thread grid
  for (int n0 = 0; n0 < NG; n0 += 128) {
    for (int idx = tid; idx < 12800; idx += 512) {
      int n = idx / 100, k = idx - n * 100;
      int jc = n0 + n;
      Bs[k][n] = (jc < NG) ? Wih[jc * 100 + k] : 0.f;
    }
    if (tid < 128) {
      int jc = n0 + tid;
      bias_s[tid] = (jc < NG) ? (bih[jc] + bhh[jc]) : 0.f;
    }
    __syncthreads();
    float acc[8][4] = {};
    #define PG_FMA(R, AX)                                                 \
      acc[R][0] = fmaf(AX, bb.x, acc[R][0]);                              \
      acc[R][1] = fmaf(AX, bb.y, acc[R][1]);                              \
      acc[R][2] = fmaf(AX, bb.z, acc[R][2]);                              \
      acc[R][3] = fmaf(AX, bb.w, acc[R][3]);
    #pragma unroll 2
    for (int k = 0; k < 100; ++k) {
      float4 a0 = *(const float4*)&As[k][tm * 4];       // 2-way, free
      float4 a1 = *(const float4*)&As[k][64 + tm * 4];
      float4 bb = *(const float4*)&Bs[k][tn * 4];       // broadcast
      PG_FMA(0, a0.x) PG_FMA(1, a0.y) PG_FMA(2, a0.z) PG_FMA(3, a0.w)
      PG_FMA(4, a1.x) PG_FMA(5, a1.y) PG_FMA(6, a1.z) PG_FMA(7, a1.w)
    }
    #undef PG_FMA
    if (n0 + tn * 4 < NG) {                      // whole float4 valid or none
      float4 bv4 = *(const float4*)&bias_s[tn * 4];
      #pragma unroll
      for (int r = 0; r < 8; ++r) {
        int m = t * 128 + ((r < 4) ? (tm * 4 + r) : (64 + tm * 4 + (r - 4)));
        float4 st;
        st.x = acc[r][0] + bv4.x; st.y = acc[r][1] + bv4.y;
        st.z = acc[r][2] + bv4.z; st.w = acc[r][3] + bv4.w;
        *(float4*)&pre[m * NG + n0 + tn * 4] = st;
      }
    }
    __syncthreads();                             // Bs safe to overwrite
  }
}

// ---------------------------------------------------------------- kernel 2
// sequential LSTM: 128 blocks (one per e-row), 512 threads. The
// harness-verified 220us structure (R0/R5/R6). R1-R4: fewer waves /
// fewer LDS instrs always lost — 200 weight floats + working set
// exceeds the 256 arch-VGPR ceiling, forcing AGPR copies at 1 wave/SIMD
// (2625cyc/step vs 2060 here). Step floor: LDS broadcast pipe
// (175 x b128 ~= 1645cyc) + update/barriers (~415).
__device__ __forceinline__ float fast_sigmoid(float x) {
  return 1.f / (1.f + __expf(-x));
}
__device__ __forceinline__ float fast_tanh(float x) {
  float ax = fabsf(x);
  float e  = __expf(-2.f * ax);
  float t  = (1.f - e) / (1.f + e);
  return x < 0.f ? -t : t;
}

#define FMA4(A, W, H)                                                     \
  A = fmaf((H).x, (W).x, A); A = fmaf((H).y, (W).y, A);                   \
  A = fmaf((H).z, (W).z, A); A = fmaf((H).w, (W).w, A)

__global__ __launch_bounds__(512, 2) void k_lstm(
    const float* __restrict__ pre, const float* __restrict__ Whh,
    const int* __restrict__ last, float* __restrict__ truh) {
  __shared__ __align__(16) float h_s[100];
  __shared__ float g_s[NG];
  __shared__ int   last_s[NB];
  const int e = blockIdx.x;         // 0..127
  const int j = threadIdx.x;        // active < 400

  // 25 named float4 = 100 weight VGPRs. Whh row stride 400 B -> 16B aligned.
  float4 w00, w01, w02, w03, w04, w05, w06, w07, w08, w09, w10, w11, w12,
         w13, w14, w15, w16, w17, w18, w19, w20, w21, w22, w23, w24;
  if (j < NG) {
    const float4* wr = (const float4*)(Whh + j * 100);
    w00 = wr[0];  w01 = wr[1];  w02 = wr[2];  w03 = wr[3];  w04 = wr[4];
    w05 = wr[5];  w06 = wr[6];  w07 = wr[7];  w08 = wr[8];  w09 = wr[9];
    w10 = wr[10]; w11 = wr[11]; w12 = wr[12]; w13 = wr[13]; w14 = wr[14];
    w15 = wr[15]; w16 = wr[16]; w17 = wr[17]; w18 = wr[18]; w19 = wr[19];
    w20 = wr[20]; w21 = wr[21]; w22 = wr[22]; w23 = wr[23]; w24 = wr[24];
  }
  if (j < NH) h_s[j] = 0.f;
  if (j < NB) last_s[j] = last[j];  // stage once; avoids per-step global read
  float c = 0.f;                    // cell state for thread j<100

  const float* pbase = pre + e * NG + j;        // + t*51200 per step
  float p0 = (j < NG) ? pbase[0]         : 0.f;
  float p1 = (j < NG) ? pbase[51200]     : 0.f;
  float p2 = (j < NG) ? pbase[2 * 51200] : 0.f;
  __syncthreads();

  for (int t = 0; t < NB; ++t) {
    float p3 = (j < NG && t + 3 < NB) ? pbase[(t + 3) * 51200] : 0.f;

    if (j < NG) {
      // 4 independent accumulator chains; h broadcast from LDS via b128.
      float a0 = p0, a1 = 0.f, a2 = 0.f, a3 = 0.f;
      const float4* h4 = (const float4*)h_s;
      float4 h;
      h = h4[0];  FMA4(a0, w00, h);
      h = h4[1];  FMA4(a1, w01, h);
      h = h4[2];  FMA4(a2, w02, h);
      h = h4[3];  FMA4(a3, w03, h);
      h = h4[4];  FMA4(a0, w04, h);
      h = h4[5];  FMA4(a1, w05, h);
      h = h4[6];  FMA4(a2, w06, h);
      h = h4[7];  FMA4(a3, w07, h);
      h = h4[8];  FMA4(a0, w08, h);
      h = h4[9];  FMA4(a1, w09, h);
      h = h4[10]; FMA4(a2, w10, h);
      h = h4[11]; FMA4(a3, w11, h);
      h = h4[12]; FMA4(a0, w12, h);
      h = h4[13]; FMA4(a1, w13, h);
      h = h4[14]; FMA4(a2, w14, h);
      h = h4[15]; FMA4(a3, w15, h);
      h = h4[16]; FMA4(a0, w16, h);
      h = h4[17]; FMA4(a1, w17, h);
      h = h4[18]; FMA4(a2, w18, h);
      h = h4[19]; FMA4(a3, w19, h);
      h = h4[20]; FMA4(a0, w20, h);
      h = h4[21]; FMA4(a1, w21, h);
      h = h4[22]; FMA4(a2, w22, h);
      h = h4[23]; FMA4(a3, w23, h);
      h = h4[24]; FMA4(a0, w24, h);
      float acc = (a0 + a1) + (a2 + a3);
      float act = (j >= 200 && j < 300) ? fast_tanh(acc) : fast_sigmoid(acc);
      g_s[j] = act;
    }
    __syncthreads();                            // gates visible

    if (j < NH) {
      float ig = g_s[j], fg = g_s[100 + j], gg = g_s[200 + j], og = g_s[300 + j];
      c = fmaf(fg, c, ig * gg);
      float h = og * fast_tanh(c);
      h_s[j] = h;
      if (j == last_s[t]) truh[t * NE + e] = h; // hs[b=t, e, last[t]]
    }
    __syncthreads();                            // h_s(t) visible for step t+1

    p0 = p1; p1 = p2; p2 = p3;
  }
}

// ---------------------------------------------------------------- kernel 3
// out[b] = sigmoid( truh[b,:] . fc_w + fc_b )
__global__ __launch_bounds__(128) void k_fc(
    const float* __restrict__ truh, const float* __restrict__ fcw,
    const float* __restrict__ fcb, float* __restrict__ out) {
  int b = blockIdx.x, t = threadIdx.x;
  float v = truh[b * NE + t] * fcw[t];
  #pragma unroll
  for (int o = 32; o > 0; o >>= 1) v += __shfl_down(v, o);
  __shared__ float s[2];
  if ((t & 63) == 0) s[t >> 6] = v;
  __syncthreads();
  if (t == 0) {
    float sum = s[0] + s[1] + fcb[0];
    out[b] = 1.f / (1.f + __expf(-sum));
  }
}

// ---------------------------------------------------------------- launch
extern "C" void kernel_launch(void* const* d_in, const int* in_sizes, int n_in,
                              void* d_out, int out_size, void* d_ws, size_t ws_size,
                              hipStream_t stream) {
  (void)in_sizes; (void)n_in; (void)out_size; (void)ws_size;
  const int*   diag  = (const int*)d_in[0];
  const float* mask  = (const float*)d_in[1];
  const float* table = (const float*)d_in[2];
  const float* Wih   = (const float*)d_in[3];
  const float* Whh   = (const float*)d_in[4];
  const float* bih   = (const float*)d_in[5];
  const float* bhh   = (const float*)d_in[6];
  const float* fcw   = (const float*)d_in[7];
  const float* fcb   = (const float*)d_in[8];

  float* ws   = (float*)d_ws;
  float* pre  = ws + OFF_PRE;
  float* truh = ws + OFF_TRUH;
  int*   last = (int*)(ws + OFF_LAST);
  float* out  = (float*)d_out;

  k_embgemm<<<dim3(NB),  dim3(512), 0, stream>>>(
      diag, mask, table, Wih, bih, bhh, pre, last);
  k_lstm   <<<dim3(NE),  dim3(512), 0, stream>>>(pre, Whh, last, truh);
  k_fc     <<<dim3(NB),  dim3(128), 0, stream>>>(truh, fcw, fcb, out);
}

// Round 9
// 378.347 us; speedup vs baseline: 1.7464x; 1.0667x over previous
//
#include <hip/hip_runtime.h>
#include <math.h>

#define NB 256      // batch / time steps
#define NV 100      // visits
#define NC 40       // codes per visit
#define NE 128      // embed dim (LSTM "batch")
#define NH 100      // hidden (== feat)
#define NG 400      // 4*NH

// ws layout (float elements)
#define OFF_PRE   0
#define N_PRE     (NB*NE*NG)                 // 13,107,200
#define OFF_TRUH  (OFF_PRE + N_PRE)
#define N_TRUH    (NB*NE)                    // 32,768
#define OFF_LAST  (OFF_TRUH + N_TRUH)        // 256 ints

// ---------------------------------------------------------------- kernel 1
// Fused embed + pregemm. 256 blocks x 512 threads, t = blockIdx.x, one
// block per CU (159.4KB LDS), full-chip in a single round.
//
// R9 changes vs R8 (both instruction-count cuts, bit-identical math):
//  - embed: mask/diag rows loaded as float4/int4 (VMEM instrs/thread
//    3000 -> 1500). Same ascending-c fmaf chain.
//  - GEMM: 8m x 8n register tiles over n-chunks {256,144} (Bs[100][264]).
//    Per k: 4 ds_read_b128 -> 64 FMAs (was 3 -> 32); per-CU b128 count
//    9600 -> 6400. A-reads 2-way same-bank/diff-addr (free), B-reads
//    16-lane same-address broadcast (free). Single k-ascending chain
//    per output + bias at store, unchanged.
__global__ __launch_bounds__(512, 2) void k_embgemm(
    const int* __restrict__ diag, const float* __restrict__ mask,
    const float* __restrict__ table, const float* __restrict__ Wih,
    const float* __restrict__ bih, const float* __restrict__ bhh,
    float* __restrict__ pre, int* __restrict__ last) {
  __shared__ __align__(16) float As[100][132];   // [k][m], 128 + 4 pad (52.8K)
  __shared__ __align__(16) float Bs[100][264];   // [k][n], 256 + 8 pad (105.6K)
  __shared__ __align__(16) float bias_s[256];
  __shared__ int lastred[4];

  const int tid = threadIdx.x;
  const int t   = blockIdx.x;                    // 0..255 == batch row
  const int e   = tid & 127;
  const int sub = tid >> 7;                      // 0..3

  // ---- embed b==t straight into As. fl = i*512 + tid; v = fl>>7,
  // e = fl&127 (const per thread). As[k][m] == x2[t*128+m][k].
  int vmax = -1;
  for (int i = 0; i < 25; ++i) {
    int fl = i * 512 + tid;
    int v  = fl >> 7;                            // 0..99
    const float4* mrow4 = (const float4*)(mask + (t * NV + v) * NC);
    const int4*   drow4 = (const int4*)(diag + (t * NV + v) * NC);
    float acc = 0.f, msum = 0.f;
    #pragma unroll
    for (int cc = 0; cc < 10; ++cc) {            // 40 codes as 10 x (f4,i4)
      float4 mm = mrow4[cc];
      int4   ii = drow4[cc];
      acc = fmaf(mm.x, table[ii.x * NE + e], acc); msum += mm.x;
      acc = fmaf(mm.y, table[ii.y * NE + e], acc); msum += mm.y;
      acc = fmaf(mm.z, table[ii.z * NE + e], acc); msum += mm.z;
      acc = fmaf(mm.w, table[ii.w * NE + e], acc); msum += mm.w;
    }
    int m = fl / 100, k = fl - m * 100;
    As[k][m] = acc;
    if (e == 0 && msum > 0.f) vmax = max(vmax, v);
  }
  if (e == 0) lastred[sub] = vmax;               // sub covers v%4==sub
  __syncthreads();                               // As + lastred ready
  if (tid == 0) {
    int l = max(max(lastred[0], lastred[1]), max(lastred[2], lastred[3]));
    last[t] = max(l, 0);
  }

  // ---- GEMM: 128m x 400n in n-chunks {0..255, 256..399(+pad)}.
  // 16tm x 32tn thread grid; thread tile = rows {tm*4+r, 64+tm*4+r} x
  // cols {tn*4+c, 128+tn*4+c}.
  const int tm = tid & 15, tn = tid >> 4;        // tn 0..31
  for (int n0 = 0; n0 < NG; n0 += 256) {
    for (int idx = tid; idx < 25600; idx += 512) {   // 50 iters
      int n = idx / 100, k = idx - n * 100;
      int jc = n0 + n;
      Bs[k][n] = (jc < NG) ? Wih[jc * 100 + k] : 0.f;  // zero-pad tail
    }
    if (tid < 256) {
      int jc = n0 + tid;
      bias_s[tid] = (jc < NG) ? (bih[jc] + bhh[jc]) : 0.f;
    }
    __syncthreads();

    float acc[8][8] = {};                        // [m-sub][n-sub]
    #define PG_ROW(R, AX)                                                 \
      acc[R][0] = fmaf(AX, b0.x, acc[R][0]);                              \
      acc[R][1] = fmaf(AX, b0.y, acc[R][1]);                              \
      acc[R][2] = fmaf(AX, b0.z, acc[R][2]);                              \
      acc[R][3] = fmaf(AX, b0.w, acc[R][3]);                              \
      acc[R][4] = fmaf(AX, b1.x, acc[R][4]);                              \
      acc[R][5] = fmaf(AX, b1.y, acc[R][5]);                              \
      acc[R][6] = fmaf(AX, b1.z, acc[R][6]);                              \
      acc[R][7] = fmaf(AX, b1.w, acc[R][7]);
    for (int k = 0; k < 100; ++k) {
      float4 a0 = *(const float4*)&As[k][tm * 4];        // 2-way, free
      float4 a1 = *(const float4*)&As[k][64 + tm * 4];   // 2-way, free
      float4 b0 = *(const float4*)&Bs[k][tn * 4];        // broadcast
      float4 b1 = *(const float4*)&Bs[k][128 + tn * 4];  // broadcast
      PG_ROW(0, a0.x) PG_ROW(1, a0.y) PG_ROW(2, a0.z) PG_ROW(3, a0.w)
      PG_ROW(4, a1.x) PG_ROW(5, a1.y) PG_ROW(6, a1.z) PG_ROW(7, a1.w)
    }
    #undef PG_ROW

    // stores: col group 0 = n0+tn*4 (always < 400 for both chunks);
    // col group 1 = n0+128+tn*4 (chunk1: valid only tn < 4).
    const int c0 = n0 + tn * 4;
    const int c1 = n0 + 128 + tn * 4;
    float4 bv0 = *(const float4*)&bias_s[tn * 4];
    float4 bv1 = *(const float4*)&bias_s[128 + tn * 4];
    #pragma unroll
    for (int r = 0; r < 8; ++r) {
      int m = t * 128 + ((r < 4) ? (tm * 4 + r) : (64 + tm * 4 + (r - 4)));
      if (c0 < NG) {
        float4 st;
        st.x = acc[r][0] + bv0.x; st.y = acc[r][1] + bv0.y;
        st.z = acc[r][2] + bv0.z; st.w = acc[r][3] + bv0.w;
        *(float4*)&pre[m * NG + c0] = st;
      }
      if (c1 < NG) {
        float4 st;
        st.x = acc[r][4] + bv1.x; st.y = acc[r][5] + bv1.y;
        st.z = acc[r][6] + bv1.z; st.w = acc[r][7] + bv1.w;
        *(float4*)&pre[m * NG + c1] = st;
      }
    }
    __syncthreads();                             // Bs safe to overwrite
  }
}

// ---------------------------------------------------------------- kernel 2
// sequential LSTM: 128 blocks (one per e-row), 512 threads. The
// harness-verified 220us structure. R1-R4: fewer waves / fewer LDS
// instrs always lost — 200 weight floats + working set exceeds the 256
// arch-VGPR ceiling, forcing AGPR copies at 1 wave/SIMD. Step floor:
// LDS broadcast pipe (175 x b128 ~= 1645cyc) + update/barriers (~415).
__device__ __forceinline__ float fast_sigmoid(float x) {
  return 1.f / (1.f + __expf(-x));
}
__device__ __forceinline__ float fast_tanh(float x) {
  float ax = fabsf(x);
  float e  = __expf(-2.f * ax);
  float t  = (1.f - e) / (1.f + e);
  return x < 0.f ? -t : t;
}

#define FMA4(A, W, H)                                                     \
  A = fmaf((H).x, (W).x, A); A = fmaf((H).y, (W).y, A);                   \
  A = fmaf((H).z, (W).z, A); A = fmaf((H).w, (W).w, A)

__global__ __launch_bounds__(512, 2) void k_lstm(
    const float* __restrict__ pre, const float* __restrict__ Whh,
    const int* __restrict__ last, float* __restrict__ truh) {
  __shared__ __align__(16) float h_s[100];
  __shared__ float g_s[NG];
  __shared__ int   last_s[NB];
  const int e = blockIdx.x;         // 0..127
  const int j = threadIdx.x;        // active < 400

  // 25 named float4 = 100 weight VGPRs. Whh row stride 400 B -> 16B aligned.
  float4 w00, w01, w02, w03, w04, w05, w06, w07, w08, w09, w10, w11, w12,
         w13, w14, w15, w16, w17, w18, w19, w20, w21, w22, w23, w24;
  if (j < NG) {
    const float4* wr = (const float4*)(Whh + j * 100);
    w00 = wr[0];  w01 = wr[1];  w02 = wr[2];  w03 = wr[3];  w04 = wr[4];
    w05 = wr[5];  w06 = wr[6];  w07 = wr[7];  w08 = wr[8];  w09 = wr[9];
    w10 = wr[10]; w11 = wr[11]; w12 = wr[12]; w13 = wr[13]; w14 = wr[14];
    w15 = wr[15]; w16 = wr[16]; w17 = wr[17]; w18 = wr[18]; w19 = wr[19];
    w20 = wr[20]; w21 = wr[21]; w22 = wr[22]; w23 = wr[23]; w24 = wr[24];
  }
  if (j < NH) h_s[j] = 0.f;
  if (j < NB) last_s[j] = last[j];  // stage once; avoids per-step global read
  float c = 0.f;                    // cell state for thread j<100

  const float* pbase = pre + e * NG + j;        // + t*51200 per step
  float p0 = (j < NG) ? pbase[0]         : 0.f;
  float p1 = (j < NG) ? pbase[51200]     : 0.f;
  float p2 = (j < NG) ? pbase[2 * 51200] : 0.f;
  __syncthreads();

  for (int t = 0; t < NB; ++t) {
    float p3 = (j < NG && t + 3 < NB) ? pbase[(t + 3) * 51200] : 0.f;

    if (j < NG) {
      // 4 independent accumulator chains; h broadcast from LDS via b128.
      float a0 = p0, a1 = 0.f, a2 = 0.f, a3 = 0.f;
      const float4* h4 = (const float4*)h_s;
      float4 h;
      h = h4[0];  FMA4(a0, w00, h);
      h = h4[1];  FMA4(a1, w01, h);
      h = h4[2];  FMA4(a2, w02, h);
      h = h4[3];  FMA4(a3, w03, h);
      h = h4[4];  FMA4(a0, w04, h);
      h = h4[5];  FMA4(a1, w05, h);
      h = h4[6];  FMA4(a2, w06, h);
      h = h4[7];  FMA4(a3, w07, h);
      h = h4[8];  FMA4(a0, w08, h);
      h = h4[9];  FMA4(a1, w09, h);
      h = h4[10]; FMA4(a2, w10, h);
      h = h4[11]; FMA4(a3, w11, h);
      h = h4[12]; FMA4(a0, w12, h);
      h = h4[13]; FMA4(a1, w13, h);
      h = h4[14]; FMA4(a2, w14, h);
      h = h4[15]; FMA4(a3, w15, h);
      h = h4[16]; FMA4(a0, w16, h);
      h = h4[17]; FMA4(a1, w17, h);
      h = h4[18]; FMA4(a2, w18, h);
      h = h4[19]; FMA4(a3, w19, h);
      h = h4[20]; FMA4(a0, w20, h);
      h = h4[21]; FMA4(a1, w21, h);
      h = h4[22]; FMA4(a2, w22, h);
      h = h4[23]; FMA4(a3, w23, h);
      h = h4[24]; FMA4(a0, w24, h);
      float acc = (a0 + a1) + (a2 + a3);
      float act = (j >= 200 && j < 300) ? fast_tanh(acc) : fast_sigmoid(acc);
      g_s[j] = act;
    }
    __syncthreads();                            // gates visible

    if (j < NH) {
      float ig = g_s[j], fg = g_s[100 + j], gg = g_s[200 + j], og = g_s[300 + j];
      c = fmaf(fg, c, ig * gg);
      float h = og * fast_tanh(c);
      h_s[j] = h;
      if (j == last_s[t]) truh[t * NE + e] = h; // hs[b=t, e, last[t]]
    }
    __syncthreads();                            // h_s(t) visible for step t+1

    p0 = p1; p1 = p2; p2 = p3;
  }
}

// ---------------------------------------------------------------- kernel 3
// out[b] = sigmoid( truh[b,:] . fc_w + fc_b )
__global__ __launch_bounds__(128) void k_fc(
    const float* __restrict__ truh, const float* __restrict__ fcw,
    const float* __restrict__ fcb, float* __restrict__ out) {
  int b = blockIdx.x, t = threadIdx.x;
  float v = truh[b * NE + t] * fcw[t];
  #pragma unroll
  for (int o = 32; o > 0; o >>= 1) v += __shfl_down(v, o);
  __shared__ float s[2];
  if ((t & 63) == 0) s[t >> 6] = v;
  __syncthreads();
  if (t == 0) {
    float sum = s[0] + s[1] + fcb[0];
    out[b] = 1.f / (1.f + __expf(-sum));
  }
}

// ---------------------------------------------------------------- launch
extern "C" void kernel_launch(void* const* d_in, const int* in_sizes, int n_in,
                              void* d_out, int out_size, void* d_ws, size_t ws_size,
                              hipStream_t stream) {
  (void)in_sizes; (void)n_in; (void)out_size; (void)ws_size;
  const int*   diag  = (const int*)d_in[0];
  const float* mask  = (const float*)d_in[1];
  const float* table = (const float*)d_in[2];
  const float* Wih   = (const float*)d_in[3];
  const float* Whh   = (const float*)d_in[4];
  const float* bih   = (const float*)d_in[5];
  const float* bhh   = (const float*)d_in[6];
  const float* fcw   = (const float*)d_in[7];
  const float* fcb   = (const float*)d_in[8];

  float* ws   = (float*)d_ws;
  float* pre  = ws + OFF_PRE;
  float* truh = ws + OFF_TRUH;
  int*   last = (int*)(ws + OFF_LAST);
  float* out  = (float*)d_out;

  k_embgemm<<<dim3(NB),  dim3(512), 0, stream>>>(
      diag, mask, table, Wih, bih, bhh, pre, last);
  k_lstm   <<<dim3(NE),  dim3(512), 0, stream>>>(pre, Whh, last, truh);
  k_fc     <<<dim3(NB),  dim3(128), 0, stream>>>(truh, fcw, fcb, out);
}